// Round 12
// baseline (171.213 us; speedup 1.0000x reference)
//
#include <hip/hip_runtime.h>

typedef unsigned short u16;
typedef unsigned int   u32;
typedef short bf16x8 __attribute__((ext_vector_type(8)));
typedef float f32x16 __attribute__((ext_vector_type(16)));
typedef unsigned int u32x2 __attribute__((ext_vector_type(2)));  // native vec for nt-store

#define S_  2048
#define D_  64
#define NR_ 4
#define NB_ 32

#define AS 72    // A tile row stride (shorts), 144 B (16B-aligned)
#define VS 136   // Vt row stride (shorts), 272 B
#define PS 136   // SM row stride (shorts), 272 B

#define LOG2E 1.44269504088896f
#define LN2   0.69314718055995f

// 2^x via the native v_exp_f32 (NOT __exp2f: collides with glibc math.h).
__device__ __forceinline__ float ex2(float x){ return __builtin_amdgcn_exp2f(x); }
// fast reciprocal (v_rcp_f32, ~1ulp) — fine for sums in [1,128] at 1.5e-2 tol.
__device__ __forceinline__ float frcp(float x){ return __builtin_amdgcn_rcpf(x); }

// packed f32x2 -> bf16x2 (RNE), lo=a hi=b. gfx950 has the INSTRUCTION
// v_cvt_pk_bf16_f32 but NO clang builtin (learn_hip m240) — inline asm.
// (R7: VALUBusy 46.6->34.3% confirmed; dur flat — k_attn is latency-bound.)
__device__ __forceinline__ u32 pk2bf(float a, float b){
  u32 r;
  asm("v_cvt_pk_bf16_f32 %0, %1, %2" : "=v"(r) : "v"(a), "v"(b));
  return r;
}
__device__ __forceinline__ void unpack2(u32 w, float &a, float &b){
  a = __uint_as_float(w<<16);
  b = __uint_as_float(w & 0xffff0000u);
}
__device__ __forceinline__ bf16x8 ld8(const u16* p){
  union { uint4 u; bf16x8 v; } x;
  x.u = *(const uint4*)p;
  return x.v;
}
// nontemporal 8B store: __builtin_nontemporal_store requires a CLANG vector
// type (ext_vector_type), not HIP's uint2 class (R11 compile fail).
__device__ __forceinline__ void nt_store8(u16* p, u32 lo, u32 hi){
  u32x2 v; v.x = lo; v.y = hi;
  __builtin_nontemporal_store(v, (u32x2*)p);
}

// ---------------------------------------------------------------------------
// K1: hash via LDS-broadcast R, 1 position/thread, acc[64]. PROVEN SHAPE
// (~20us = per-CU LDS-issue floor). R8's scalar-R variant regressed 3x
// (SGPR re-issue serialization, VALUBusy 8.8%); >64 acc spills; round-split
// thrashes L2. Do not revisit.
// ---------------------------------------------------------------------------
__global__ __launch_bounds__(256, 2) void k_hash(const float* __restrict__ q,
                                                 const float* __restrict__ v,
                                                 const float* __restrict__ R,
                                                 int* __restrict__ hout,
                                                 u16* __restrict__ qb,
                                                 u16* __restrict__ vbuf,
                                                 float* __restrict__ scq){
  __shared__ float Rl[4096];               // [d][r*16+k] row-major, f32
  int b   = blockIdx.x >> 3;
  int pos = (blockIdx.x & 7) * 256 + threadIdx.x;

  { // stage R (coalesced)
    const float4* Rg = (const float4*)(R + (size_t)b * 4096);
    float4* Rs = (float4*)Rl;
    #pragma unroll
    for (int k = 0; k < 4; k++) Rs[k*256 + threadIdx.x] = Rg[k*256 + threadIdx.x];
  }
  __syncthreads();

  const float4* q4 = (const float4*)(q + ((size_t)b * S_ + pos) * D_);
  const float4* v4 = (const float4*)(v + ((size_t)b * S_ + pos) * D_);
  uint2* qw = (uint2*)(qb   + ((size_t)b * S_ + pos) * D_);
  uint2* vw = (uint2*)(vbuf + ((size_t)b * S_ + pos) * D_);

  float acc[64];
  #pragma unroll
  for (int i = 0; i < 64; i++) acc[i] = 0.f;
  float ss = 0.f;

  #pragma unroll 4
  for (int c = 0; c < 16; c++){
    float4 wa = q4[c];
    float4 xa = v4[c];
    ss += wa.x*wa.x + wa.y*wa.y + wa.z*wa.z + wa.w*wa.w;
    qw[c] = make_uint2(pk2bf(wa.x, wa.y), pk2bf(wa.z, wa.w));
    vw[c] = make_uint2(pk2bf(xa.x, xa.y), pk2bf(xa.z, xa.w));
    float qa[4] = {wa.x, wa.y, wa.z, wa.w};
    #pragma unroll
    for (int dd = 0; dd < 4; dd++){
      int d = c * 4 + dd;
      const float4* Rr = (const float4*)(&Rl[d * 64]);
      #pragma unroll
      for (int k4 = 0; k4 < 16; k4++){
        float4 rv = Rr[k4];      // broadcast (same addr all lanes) — conflict-free
        acc[k4*4+0] += qa[dd] * rv.x;
        acc[k4*4+1] += qa[dd] * rv.y;
        acc[k4*4+2] += qa[dd] * rv.z;
        acc[k4*4+3] += qa[dd] * rv.w;
      }
    }
  }
  // 0.125 = 1/sqrt(d); LOG2E folds the exp2-domain conversion into the scale.
  scq[(size_t)b * S_ + pos] = rsqrtf(fmaxf(ss, 1e-12f)) * 0.125f * LOG2E;

  #pragma unroll
  for (int r = 0; r < 4; r++){
    float bv = acc[r*16]; int bi = 0;
    #pragma unroll
    for (int m = 1; m < 32; m++){
      float vv = (m < 16) ? acc[r*16 + m] : -acc[r*16 + m - 16];
      if (vv > bv){ bv = vv; bi = m; }   // strict >: first max wins
    }
    hout[((size_t)b * NR_ + r) * S_ + pos] = bi;
  }
}

// ---------------------------------------------------------------------------
// K2: stable counting sort on 32 bins per (b,r).
// ---------------------------------------------------------------------------
__global__ __launch_bounds__(256) void k_sort(const int* __restrict__ h,
                                              int* __restrict__ sidx,
                                              int* __restrict__ chk){
  __shared__ int cnt[32][257];
  __shared__ int base[32];
  int br = blockIdx.x;
  const int* hb = h + (size_t)br * S_;
  int t = threadIdx.x;

  #pragma unroll
  for (int hh = 0; hh < 32; hh++) cnt[hh][t] = 0;
  __syncthreads();

  int hv[8];
  const int4* hb4 = (const int4*)hb;
  int4 a0 = hb4[t*2], a1 = hb4[t*2+1];
  hv[0]=a0.x; hv[1]=a0.y; hv[2]=a0.z; hv[3]=a0.w;
  hv[4]=a1.x; hv[5]=a1.y; hv[6]=a1.z; hv[7]=a1.w;
  #pragma unroll
  for (int k = 0; k < 8; k++) cnt[hv[k]][t]++;
  __syncthreads();

  int wave = t >> 6, lane = t & 63;
  for (int hh = wave*8; hh < wave*8 + 8; hh++){
    int vals[4]; int s0 = 0;
    #pragma unroll
    for (int k = 0; k < 4; k++){ vals[k] = cnt[hh][lane*4+k]; s0 += vals[k]; }
    int incl = s0;
    #pragma unroll
    for (int off = 1; off < 64; off <<= 1){
      int o = __shfl_up(incl, off, 64);
      if (lane >= off) incl += o;
    }
    int run = incl - s0;
    #pragma unroll
    for (int k = 0; k < 4; k++){ int tmp = vals[k]; cnt[hh][lane*4+k] = run; run += tmp; }
    if (lane == 63) base[hh] = incl;
  }
  __syncthreads();
  if (t == 0){
    int run = 0;
    #pragma unroll
    for (int hh = 0; hh < 32; hh++){ int tot = base[hh]; base[hh] = run; run += tot; }
  }
  __syncthreads();

  int p0 = t * 8;
  #pragma unroll
  for (int k = 0; k < 8; k++){
    int hh = hv[k];
    int c = cnt[hh][t];
    int slot = base[hh] + c;
    cnt[hh][t] = c + 1;
    sidx[(size_t)br * S_ + slot]    = p0 + k;
    chk [(size_t)br * S_ + p0 + k]  = slot >> 6;
  }
}

// ---------------------------------------------------------------------------
// K3: per (b, r, bucket n): MFMA attention, PROVEN R9 structure (~41us;
// session best total 147.4). XCD swizzle A/B-confirmed (+3.5us total).
// R10's 2-tuple/block restructure FAILED correctness (absmax 3.08) with no
// locatable race — reverted, do not re-attempt without device-side debug.
// R12 = R11 retry (fixed compile): att_ws scatter uses NONTEMPORAL stores —
// 38MB of streaming output no longer evicts qb/vbuf/sidx/chk from L2;
// gather L2-hit-rate is on the critical path (swizzle win proved it).
// ---------------------------------------------------------------------------
__global__ __launch_bounds__(256, 4) void k_attn(const u16* __restrict__ qb,
                                                 const u16* __restrict__ vb,
                                                 const int* __restrict__ sidx,
                                                 const int* __restrict__ chk,
                                                 const float* __restrict__ scq,
                                                 float* __restrict__ lse_ws,
                                                 u16*  __restrict__ att_ws){
  __shared__ u16 A[128*AS];      // Q/K tile row-major; later Vt[64][VS] (d-major)
  __shared__ u16 SM[64*PS];      // probabilities (bf16), row i, col j
  __shared__ int   pkey[128];
  __shared__ float rcnt[128];
  __shared__ float sc[128];
  __shared__ float pm[4*64];     // per (jtile, i) partial max (log2 domain)
  __shared__ float ps[4*64];     // per (jtile, i) partial sum

  int blk0 = blockIdx.x;
  int blk  = (blk0 & 7) * 512 + (blk0 >> 3);   // XCD chunked swizzle (bijective)
  int b = blk >> 7, r = (blk >> 5) & 3, n = blk & 31;
  int npv = (n + 31) & 31;
  int t = threadIdx.x;
  int lane = t & 63, w = t >> 6;
  int la = lane & 31, hh = lane >> 5;
  int coff = hh * 8;
  const int* sb = sidx + ((size_t)b * NR_ + r) * S_;

  int pmine = 0;
  if (t < 128){
    pmine = (t < 64) ? sb[npv*64 + t] : sb[n*64 + (t - 64)];
    pkey[t] = pmine;
  }
  __syncthreads();

  // ---- phase 1: issue Q/K + V gathers; overlap rcnt/sc scatters ----------
  uint4 qk0, qk1, qk2, qk3;
  {
    int row = t >> 1, half = t & 1;
    const uint4* src = (const uint4*)(qb + ((size_t)b*S_ + pkey[row])*D_) + half*4;
    qk0 = src[0]; qk1 = src[1]; qk2 = src[2]; qk3 = src[3];
  }
  int jp = t & 63, dgrp = t >> 6;   // V: key pair (2jp,2jp+1), d-range dgrp*16..+15
  uint4 va0, va1, vb0, vb1;
  {
    const uint4* s0 = (const uint4*)(vb + ((size_t)b*S_ + pkey[2*jp  ])*D_ + dgrp*16);
    const uint4* s1 = (const uint4*)(vb + ((size_t)b*S_ + pkey[2*jp+1])*D_ + dgrp*16);
    va0 = s0[0]; va1 = s0[1]; vb0 = s1[0]; vb1 = s1[1];
  }
  // rcnt/sc scatters fly concurrently with the gathers above
  if (t < 128){
    int c = 0;
    #pragma unroll
    for (int rr = 0; rr < 4; rr++){
      int ch = chk[((size_t)b * NR_ + rr) * S_ + pmine];
      c += (ch == n) || (ch == npv);
    }
    if (c < 1) c = 1;
    rcnt[t] = frcp((float)c);
    sc[t] = scq[(size_t)b * S_ + pmine];
  }
  { // LDS-stage Q/K from regs
    int row = t >> 1, half = t & 1;
    uint4* dst = (uint4*)(&A[row*AS + half*32]);
    dst[0] = qk0; dst[1] = qk1; dst[2] = qk2; dst[3] = qk3;
  }
  __syncthreads();

  // ---- phase 2: S^T = K.Q^T via MFMA; mask+exp in registers; partials -----
  float e0[16], e1[16];            // exp2(x - m_loc), live across the barrier
  float ml0, ml1;                  // per-lane local maxima (log2 domain)
  {
    int jt = w;                         // j-tile 0..3
    f32x16 acc0, acc1;                  // i = la, i = 32+la
    #pragma unroll
    for (int i = 0; i < 16; i++){ acc0[i] = 0.f; acc1[i] = 0.f; }
    int arow  = (jt*32 + la) * AS;      // K row j
    int brow0 = (64 + la) * AS;         // Q row i (0..31)
    int brow1 = (96 + la) * AS;         // Q row i (32..63)
    __builtin_amdgcn_s_setprio(1);
    #pragma unroll
    for (int ks = 0; ks < 4; ks++){
      int o = ks*16 + coff;
      bf16x8 af = ld8(&A[arow  + o]);
      bf16x8 b0 = ld8(&A[brow0 + o]);
      bf16x8 b1 = ld8(&A[brow1 + o]);
      acc0 = __builtin_amdgcn_mfma_f32_32x32x16_bf16(af, b0, acc0, 0, 0, 0);
      acc1 = __builtin_amdgcn_mfma_f32_32x32x16_bf16(af, b1, acc1, 0, 0, 0);
    }
    __builtin_amdgcn_s_setprio(0);
    int pj[16]; float scj[16];
    #pragma unroll
    for (int g = 0; g < 4; g++){
      int j0 = jt*32 + g*8 + 4*hh;           // multiple of 4 -> 16B aligned
      int4   pv  = *(const int4*)(&pkey[j0]);
      float4 sv  = *(const float4*)(&sc[j0]);
      pj[g*4+0]=pv.x; pj[g*4+1]=pv.y; pj[g*4+2]=pv.z; pj[g*4+3]=pv.w;
      scj[g*4+0]=sv.x; scj[g*4+1]=sv.y; scj[g*4+2]=sv.z; scj[g*4+3]=sv.w;
    }
    int pi0 = pkey[64 + la], pi1 = pkey[96 + la];
    float x0[16], x1[16];
    #pragma unroll
    for (int reg = 0; reg < 16; reg++){
      float a0v = acc0[reg] * scj[reg];
      float a1v = acc1[reg] * scj[reg];
      // mask constants pre-scaled by LOG2E (exp2 domain)
      if (pi0 < pj[reg]) a0v = -1442695040.0f; else if (pi0 == pj[reg]) a0v = -144269.504f;
      if (pi1 < pj[reg]) a1v = -1442695040.0f; else if (pi1 == pj[reg]) a1v = -144269.504f;
      x0[reg] = a0v; x1[reg] = a1v;
    }
    { // pairwise max tree (depth 4; clang fuses to v_max3)
      float u0 = fmaxf(fmaxf(x0[0],x0[1]), fmaxf(x0[2],x0[3]));
      float u1 = fmaxf(fmaxf(x0[4],x0[5]), fmaxf(x0[6],x0[7]));
      float u2 = fmaxf(fmaxf(x0[8],x0[9]), fmaxf(x0[10],x0[11]));
      float u3 = fmaxf(fmaxf(x0[12],x0[13]), fmaxf(x0[14],x0[15]));
      ml0 = fmaxf(fmaxf(u0,u1), fmaxf(u2,u3));
      float w0 = fmaxf(fmaxf(x1[0],x1[1]), fmaxf(x1[2],x1[3]));
      float w1 = fmaxf(fmaxf(x1[4],x1[5]), fmaxf(x1[6],x1[7]));
      float w2 = fmaxf(fmaxf(x1[8],x1[9]), fmaxf(x1[10],x1[11]));
      float w3 = fmaxf(fmaxf(x1[12],x1[13]), fmaxf(x1[14],x1[15]));
      ml1 = fmaxf(fmaxf(w0,w1), fmaxf(w2,w3));
    }
    #pragma unroll
    for (int reg = 0; reg < 16; reg++){
      e0[reg] = ex2(x0[reg] - ml0);
      e1[reg] = ex2(x1[reg] - ml1);
    }
    // pairwise sum trees
    float s0, s1;
    {
      float u0 = (e0[0]+e0[1])+(e0[2]+e0[3]);
      float u1 = (e0[4]+e0[5])+(e0[6]+e0[7]);
      float u2 = (e0[8]+e0[9])+(e0[10]+e0[11]);
      float u3 = (e0[12]+e0[13])+(e0[14]+e0[15]);
      s0 = (u0+u1)+(u2+u3);
      float w0 = (e1[0]+e1[1])+(e1[2]+e1[3]);
      float w1 = (e1[4]+e1[5])+(e1[6]+e1[7]);
      float w2 = (e1[8]+e1[9])+(e1[10]+e1[11]);
      float w3 = (e1[12]+e1[13])+(e1[14]+e1[15]);
      s1 = (w0+w1)+(w2+w3);
    }
    // combine the two hh halves (same i, disjoint j) within the wave
    float om0 = __shfl_xor(ml0, 32, 64), os0 = __shfl_xor(s0, 32, 64);
    float om1 = __shfl_xor(ml1, 32, 64), os1 = __shfl_xor(s1, 32, 64);
    float m20 = fmaxf(ml0, om0);
    float m21 = fmaxf(ml1, om1);
    float s20 = s0 * ex2(ml0 - m20) + os0 * ex2(om0 - m20);
    float s21 = s1 * ex2(ml1 - m21) + os1 * ex2(om1 - m21);
    if (hh == 0){
      pm[jt*64 + la]      = m20;  ps[jt*64 + la]      = s20;
      pm[jt*64 + 32 + la] = m21;  ps[jt*64 + 32 + la] = s21;
    }
  }
  __syncthreads();

  // ---- phase 3: finalize softmax from partials, write probs; Vt build -----
  {
    int jt = w;
    // global (m, s) for i = la and i = 32+la
    float mg0 = pm[la],      mg1 = pm[32 + la];
    #pragma unroll
    for (int k = 1; k < 4; k++){
      mg0 = fmaxf(mg0, pm[k*64 + la]);
      mg1 = fmaxf(mg1, pm[k*64 + 32 + la]);
    }
    float sg0 = 0.f, sg1 = 0.f;
    #pragma unroll
    for (int k = 0; k < 4; k++){
      sg0 += ps[k*64 + la]      * ex2(pm[k*64 + la]      - mg0);
      sg1 += ps[k*64 + 32 + la] * ex2(pm[k*64 + 32 + la] - mg1);
    }
    float f0 = ex2(ml0 - mg0) * frcp(sg0);
    float f1 = ex2(ml1 - mg1) * frcp(sg1);
    #pragma unroll
    for (int g = 0; g < 4; g++){
      int j0 = jt*32 + g*8 + 4*hh;
      float4 rc = *(const float4*)(&rcnt[j0]);
      float p00 = e0[g*4+0]*f0*rc.x, p01 = e0[g*4+1]*f0*rc.y;
      float p02 = e0[g*4+2]*f0*rc.z, p03 = e0[g*4+3]*f0*rc.w;
      float p10 = e1[g*4+0]*f1*rc.x, p11 = e1[g*4+1]*f1*rc.y;
      float p12 = e1[g*4+2]*f1*rc.z, p13 = e1[g*4+3]*f1*rc.w;
      *(uint2*)(&SM[la*PS + j0])        = make_uint2(pk2bf(p00,p01), pk2bf(p02,p03));
      *(uint2*)(&SM[(32+la)*PS + j0])   = make_uint2(pk2bf(p10,p11), pk2bf(p12,p13));
    }
    if (w == 0 && hh == 0){
      // lse in natural-log domain: mg is log2, sg is domain-invariant
      lse_ws[((size_t)b*S_ + pkey[64 + la])*NR_ + r] = mg0 * LN2 + __logf(sg0);
      lse_ws[((size_t)b*S_ + pkey[96 + la])*NR_ + r] = mg1 * LN2 + __logf(sg1);
    }
  }
  { // Vt = V^T (pure bf16 interleave), overwriting A (reads done pre-barrier)
    u32 au[8] = {va0.x, va0.y, va0.z, va0.w, va1.x, va1.y, va1.z, va1.w};
    u32 bu[8] = {vb0.x, vb0.y, vb0.z, vb0.w, vb1.x, vb1.y, vb1.z, vb1.w};
    u32* vtp = (u32*)A;
    #pragma unroll
    for (int k = 0; k < 8; k++){
      int d0 = dgrp*16 + 2*k;
      u32 even = (au[k] & 0xffffu) | (bu[k] << 16);
      u32 odd  = (au[k] >> 16)     | (bu[k] & 0xffff0000u);
      vtp[ d0      * (VS/2) + jp] = even;
      vtp[(d0 + 1) * (VS/2) + jp] = odd;
    }
  }
  __syncthreads();

  // ---- phase 5: out^T = Vt.P^T via MFMA (M=d, N=i), nontemporal scatter ---
  {
    int Mt2 = w >> 1, Nt2 = w & 1;
    f32x16 acc;
    #pragma unroll
    for (int i = 0; i < 16; i++) acc[i] = 0.f;
    int arow = (Mt2*32 + la) * VS;      // Vt row d, j contig
    int brow = (Nt2*32 + la) * PS;      // P row i, j contig
    __builtin_amdgcn_s_setprio(1);
    #pragma unroll
    for (int ks = 0; ks < 8; ks++){
      int o = ks*16 + coff;
      bf16x8 af = ld8(&A[arow + o]);
      bf16x8 bf = ld8(&SM[brow + o]);
      acc = __builtin_amdgcn_mfma_f32_32x32x16_bf16(af, bf, acc, 0, 0, 0);
    }
    __builtin_amdgcn_s_setprio(0);
    // C col = i (lane), rows = d (regs, 4 groups of 4 contiguous)
    int i = Nt2*32 + la;
    int p = pkey[64 + i];
    u16* base = att_ws + (((size_t)b*S_ + p)*NR_ + r)*D_ + Mt2*32 + 4*hh;
    #pragma unroll
    for (int g = 0; g < 4; g++){
      nt_store8(base + g*8,
                pk2bf(acc[4*g+0], acc[4*g+1]),
                pk2bf(acc[4*g+2], acc[4*g+3]));   // nt: keep att out of L2
    }
  }
}

// ---------------------------------------------------------------------------
// K4: per position softmax over round LSEs, weighted sum of round outputs.
// 4 outputs per thread (uint2 att reads, float4 out writes). grid 4096.
// ---------------------------------------------------------------------------
__global__ __launch_bounds__(256) void k_comb(const float* __restrict__ lse_ws,
                                              const u16* __restrict__ att_ws,
                                              float* __restrict__ out){
  size_t idx4 = (size_t)blockIdx.x * 256 + threadIdx.x;  // over B*S*D/4
  size_t pd = idx4 >> 4;
  int d0 = (int)(idx4 & 15) * 4;
  float4 lv = *(const float4*)(lse_ws + pd * 4);
  float m = fmaxf(fmaxf(lv.x, lv.y), fmaxf(lv.z, lv.w));
  float e0 = __expf(lv.x - m), e1 = __expf(lv.y - m);
  float e2 = __expf(lv.z - m), e3 = __expf(lv.w - m);
  float inv = frcp(e0 + e1 + e2 + e3);
  e0 *= inv; e1 *= inv; e2 *= inv; e3 *= inv;
  const u16* a = att_ws + pd * 256 + d0;
  uint2 u0 = *(const uint2*)(a);
  uint2 u1 = *(const uint2*)(a + 64);
  uint2 u2 = *(const uint2*)(a + 128);
  uint2 u3 = *(const uint2*)(a + 192);
  float4 o;
  float a0,b0,a1,b1,a2,b2,a3,b3;
  unpack2(u0.x,a0,b0); unpack2(u1.x,a1,b1); unpack2(u2.x,a2,b2); unpack2(u3.x,a3,b3);
  o.x = a0*e0 + a1*e1 + a2*e2 + a3*e3;
  o.y = b0*e0 + b1*e1 + b2*e2 + b3*e3;
  unpack2(u0.y,a0,b0); unpack2(u1.y,a1,b1); unpack2(u2.y,a2,b2); unpack2(u3.y,a3,b3);
  o.z = a0*e0 + a1*e1 + a2*e2 + a3*e3;
  o.w = b0*e0 + b1*e1 + b2*e2 + b3*e3;
  *(float4*)(out + pd * D_ + d0) = o;
}

// ---------------------------------------------------------------------------
extern "C" void kernel_launch(void* const* d_in, const int* in_sizes, int n_in,
                              void* d_out, int out_size, void* d_ws, size_t ws_size,
                              hipStream_t stream){
  const float* q = (const float*)d_in[0];   // (32,2048,64) f32
  const float* v = (const float*)d_in[1];   // (32,2048,64) f32
  const float* R = (const float*)d_in[2];   // (32,64,4,16) f32

  char* w = (char*)d_ws;
  int*   h    = (int*)  (w + 0);                     // 1 MB
  int*   sidx = (int*)  (w + (size_t)(1u << 20));    // 1 MB
  int*   chkA = (int*)  (w + (size_t)(2u << 20));    // 1 MB
  float* lse  = (float*)(w + (size_t)(3u << 20));    // 1 MB
  u16*   att  = (u16*)  (w + (size_t)(4u << 20));    // 32 MB
  u16*   qb   = (u16*)  (w + (size_t)(36u << 20));   // 8 MB bf16 q
  u16*   vbuf = (u16*)  (w + (size_t)(44u << 20));   // 8 MB bf16 v
  float* scq  = (float*)(w + (size_t)(52u << 20));   // 256 KB
  float* out  = (float*)d_out;

  k_hash <<<256,  256, 0, stream>>>(q, v, R, h, qb, vbuf, scq);
  k_sort <<<128,  256, 0, stream>>>(h, sidx, chkA);
  k_attn <<<4096, 256, 0, stream>>>(qb, vbuf, sidx, chkA, scq, lse, att);
  k_comb <<<4096, 256, 0, stream>>>(lse, att, out);
}

// Round 13
// 142.261 us; speedup vs baseline: 1.2035x; 1.2035x over previous
//
#include <hip/hip_runtime.h>

typedef unsigned short u16;
typedef unsigned int   u32;
typedef short bf16x8 __attribute__((ext_vector_type(8)));
typedef float f32x16 __attribute__((ext_vector_type(16)));
typedef unsigned int u32x4v __attribute__((ext_vector_type(4)));  // native vec for nt-store

#define S_  2048
#define D_  64
#define NR_ 4
#define NB_ 32

#define AS 72    // A tile row stride (shorts), 144 B (16B-aligned)
#define VS 136   // Vt row stride (shorts), 272 B
#define PS 136   // SM row stride (shorts), 272 B
#define OS 72    // out-transpose stride in SM2 (shorts), 144 B, 16B-aligned

#define LOG2E 1.44269504088896f
#define LN2   0.69314718055995f

// 2^x via the native v_exp_f32 (NOT __exp2f: collides with glibc math.h).
__device__ __forceinline__ float ex2(float x){ return __builtin_amdgcn_exp2f(x); }
// fast reciprocal (v_rcp_f32, ~1ulp) — fine for sums in [1,128] at 1.5e-2 tol.
__device__ __forceinline__ float frcp(float x){ return __builtin_amdgcn_rcpf(x); }

// packed f32x2 -> bf16x2 (RNE), lo=a hi=b. gfx950 has the INSTRUCTION
// v_cvt_pk_bf16_f32 but NO clang builtin (learn_hip m240) — inline asm.
__device__ __forceinline__ u32 pk2bf(float a, float b){
  u32 r;
  asm("v_cvt_pk_bf16_f32 %0, %1, %2" : "=v"(r) : "v"(a), "v"(b));
  return r;
}
__device__ __forceinline__ void unpack2(u32 w, float &a, float &b){
  a = __uint_as_float(w<<16);
  b = __uint_as_float(w & 0xffff0000u);
}
__device__ __forceinline__ bf16x8 ld8(const u16* p){
  union { uint4 u; bf16x8 v; } x;
  x.u = *(const uint4*)p;
  return x.v;
}
// nontemporal 16B store (clang ext_vector_type required, not HIP uint4).
__device__ __forceinline__ void nt_store16(u16* p, uint4 v){
  u32x4v x; x.x = v.x; x.y = v.y; x.z = v.z; x.w = v.w;
  __builtin_nontemporal_store(x, (u32x4v*)p);
}

// ---------------------------------------------------------------------------
// K1: hash via LDS-broadcast R, 1 position/thread, acc[64]. PROVEN SHAPE
// (~20us = per-CU LDS-issue floor). R8's scalar-R variant regressed 3x; >64
// acc spills; round-split thrashes L2. Do not revisit.
// ---------------------------------------------------------------------------
__global__ __launch_bounds__(256, 2) void k_hash(const float* __restrict__ q,
                                                 const float* __restrict__ v,
                                                 const float* __restrict__ R,
                                                 int* __restrict__ hout,
                                                 u16* __restrict__ qb,
                                                 u16* __restrict__ vbuf,
                                                 float* __restrict__ scq){
  __shared__ float Rl[4096];               // [d][r*16+k] row-major, f32
  int b   = blockIdx.x >> 3;
  int pos = (blockIdx.x & 7) * 256 + threadIdx.x;

  { // stage R (coalesced)
    const float4* Rg = (const float4*)(R + (size_t)b * 4096);
    float4* Rs = (float4*)Rl;
    #pragma unroll
    for (int k = 0; k < 4; k++) Rs[k*256 + threadIdx.x] = Rg[k*256 + threadIdx.x];
  }
  __syncthreads();

  const float4* q4 = (const float4*)(q + ((size_t)b * S_ + pos) * D_);
  const float4* v4 = (const float4*)(v + ((size_t)b * S_ + pos) * D_);
  uint2* qw = (uint2*)(qb   + ((size_t)b * S_ + pos) * D_);
  uint2* vw = (uint2*)(vbuf + ((size_t)b * S_ + pos) * D_);

  float acc[64];
  #pragma unroll
  for (int i = 0; i < 64; i++) acc[i] = 0.f;
  float ss = 0.f;

  #pragma unroll 4
  for (int c = 0; c < 16; c++){
    float4 wa = q4[c];
    float4 xa = v4[c];
    ss += wa.x*wa.x + wa.y*wa.y + wa.z*wa.z + wa.w*wa.w;
    qw[c] = make_uint2(pk2bf(wa.x, wa.y), pk2bf(wa.z, wa.w));
    vw[c] = make_uint2(pk2bf(xa.x, xa.y), pk2bf(xa.z, xa.w));
    float qa[4] = {wa.x, wa.y, wa.z, wa.w};
    #pragma unroll
    for (int dd = 0; dd < 4; dd++){
      int d = c * 4 + dd;
      const float4* Rr = (const float4*)(&Rl[d * 64]);
      #pragma unroll
      for (int k4 = 0; k4 < 16; k4++){
        float4 rv = Rr[k4];      // broadcast (same addr all lanes) — conflict-free
        acc[k4*4+0] += qa[dd] * rv.x;
        acc[k4*4+1] += qa[dd] * rv.y;
        acc[k4*4+2] += qa[dd] * rv.z;
        acc[k4*4+3] += qa[dd] * rv.w;
      }
    }
  }
  // 0.125 = 1/sqrt(d); LOG2E folds the exp2-domain conversion into the scale.
  scq[(size_t)b * S_ + pos] = rsqrtf(fmaxf(ss, 1e-12f)) * 0.125f * LOG2E;

  #pragma unroll
  for (int r = 0; r < 4; r++){
    float bv = acc[r*16]; int bi = 0;
    #pragma unroll
    for (int m = 1; m < 32; m++){
      float vv = (m < 16) ? acc[r*16 + m] : -acc[r*16 + m - 16];
      if (vv > bv){ bv = vv; bi = m; }   // strict >: first max wins
    }
    hout[((size_t)b * NR_ + r) * S_ + pos] = bi;
  }
}

// ---------------------------------------------------------------------------
// K2: stable counting sort on 32 bins per (b,r). R13: chk now stores the
// FULL slot (not slot>>6) — k_attn shifts; k_comb uses it to index the new
// slot-major att layout.
// ---------------------------------------------------------------------------
__global__ __launch_bounds__(256) void k_sort(const int* __restrict__ h,
                                              int* __restrict__ sidx,
                                              int* __restrict__ chk){
  __shared__ int cnt[32][257];
  __shared__ int base[32];
  int br = blockIdx.x;
  const int* hb = h + (size_t)br * S_;
  int t = threadIdx.x;

  #pragma unroll
  for (int hh = 0; hh < 32; hh++) cnt[hh][t] = 0;
  __syncthreads();

  int hv[8];
  const int4* hb4 = (const int4*)hb;
  int4 a0 = hb4[t*2], a1 = hb4[t*2+1];
  hv[0]=a0.x; hv[1]=a0.y; hv[2]=a0.z; hv[3]=a0.w;
  hv[4]=a1.x; hv[5]=a1.y; hv[6]=a1.z; hv[7]=a1.w;
  #pragma unroll
  for (int k = 0; k < 8; k++) cnt[hv[k]][t]++;
  __syncthreads();

  int wave = t >> 6, lane = t & 63;
  for (int hh = wave*8; hh < wave*8 + 8; hh++){
    int vals[4]; int s0 = 0;
    #pragma unroll
    for (int k = 0; k < 4; k++){ vals[k] = cnt[hh][lane*4+k]; s0 += vals[k]; }
    int incl = s0;
    #pragma unroll
    for (int off = 1; off < 64; off <<= 1){
      int o = __shfl_up(incl, off, 64);
      if (lane >= off) incl += o;
    }
    int run = incl - s0;
    #pragma unroll
    for (int k = 0; k < 4; k++){ int tmp = vals[k]; cnt[hh][lane*4+k] = run; run += tmp; }
    if (lane == 63) base[hh] = incl;
  }
  __syncthreads();
  if (t == 0){
    int run = 0;
    #pragma unroll
    for (int hh = 0; hh < 32; hh++){ int tot = base[hh]; base[hh] = run; run += tot; }
  }
  __syncthreads();

  int p0 = t * 8;
  #pragma unroll
  for (int k = 0; k < 8; k++){
    int hh = hv[k];
    int c = cnt[hh][t];
    int slot = base[hh] + c;
    cnt[hh][t] = c + 1;
    sidx[(size_t)br * S_ + slot]    = p0 + k;
    chk [(size_t)br * S_ + p0 + k]  = slot;      // FULL slot (R13)
  }
}

// ---------------------------------------------------------------------------
// K3: per (b, r, bucket n): MFMA attention, PROVEN R9 compute structure.
// R12 decomposed the memory problem: nt-scatter cut FETCH 51->9.4MB (L2
// pollution from att write-allocations was real) but 8B-piece nt stores
// amplified WRITE 38->104MB (no line combining). R13 gets both: att is
// stored SLOT-MAJOR (query i of block (b,r,n) is exactly slot n*64+i ->
// each block's 64 rows are 8KB contiguous); the C-fragments are transposed
// through the dead SM buffer, then nt-stored as contiguous 1KB/wave runs
// (full 64B lines, no amplification, no L2 pollution).
// ---------------------------------------------------------------------------
__global__ __launch_bounds__(256, 4) void k_attn(const u16* __restrict__ qb,
                                                 const u16* __restrict__ vb,
                                                 const int* __restrict__ sidx,
                                                 const int* __restrict__ chk,
                                                 const float* __restrict__ scq,
                                                 float* __restrict__ lse_ws,
                                                 u16*  __restrict__ att_ws){
  __shared__ u16 A[128*AS];      // Q/K tile row-major; later Vt[64][VS] (d-major)
  __shared__ u16 SM[64*PS];      // probs (bf16); later out^T transpose [i][OS]
  __shared__ int   pkey[128];
  __shared__ float rcnt[128];
  __shared__ float sc[128];
  __shared__ float pm[4*64];     // per (jtile, i) partial max (log2 domain)
  __shared__ float ps[4*64];     // per (jtile, i) partial sum

  int blk0 = blockIdx.x;
  int blk  = (blk0 & 7) * 512 + (blk0 >> 3);   // XCD chunked swizzle (bijective)
  int b = blk >> 7, r = (blk >> 5) & 3, n = blk & 31;
  int npv = (n + 31) & 31;
  int t = threadIdx.x;
  int lane = t & 63, w = t >> 6;
  int la = lane & 31, hh = lane >> 5;
  int coff = hh * 8;
  const int* sb = sidx + ((size_t)b * NR_ + r) * S_;

  int pmine = 0;
  if (t < 128){
    pmine = (t < 64) ? sb[npv*64 + t] : sb[n*64 + (t - 64)];
    pkey[t] = pmine;
  }
  __syncthreads();

  // ---- phase 1: issue Q/K + V gathers; overlap rcnt/sc scatters ----------
  uint4 qk0, qk1, qk2, qk3;
  {
    int row = t >> 1, half = t & 1;
    const uint4* src = (const uint4*)(qb + ((size_t)b*S_ + pkey[row])*D_) + half*4;
    qk0 = src[0]; qk1 = src[1]; qk2 = src[2]; qk3 = src[3];
  }
  int jp = t & 63, dgrp = t >> 6;   // V: key pair (2jp,2jp+1), d-range dgrp*16..+15
  uint4 va0, va1, vb0, vb1;
  {
    const uint4* s0 = (const uint4*)(vb + ((size_t)b*S_ + pkey[2*jp  ])*D_ + dgrp*16);
    const uint4* s1 = (const uint4*)(vb + ((size_t)b*S_ + pkey[2*jp+1])*D_ + dgrp*16);
    va0 = s0[0]; va1 = s0[1]; vb0 = s1[0]; vb1 = s1[1];
  }
  // rcnt/sc scatters fly concurrently with the gathers above
  if (t < 128){
    int c = 0;
    #pragma unroll
    for (int rr = 0; rr < 4; rr++){
      int ch = chk[((size_t)b * NR_ + rr) * S_ + pmine] >> 6;   // slot->bucket
      c += (ch == n) || (ch == npv);
    }
    if (c < 1) c = 1;
    rcnt[t] = frcp((float)c);
    sc[t] = scq[(size_t)b * S_ + pmine];
  }
  { // LDS-stage Q/K from regs
    int row = t >> 1, half = t & 1;
    uint4* dst = (uint4*)(&A[row*AS + half*32]);
    dst[0] = qk0; dst[1] = qk1; dst[2] = qk2; dst[3] = qk3;
  }
  __syncthreads();

  // ---- phase 2: S^T = K.Q^T via MFMA; mask+exp in registers; partials -----
  float e0[16], e1[16];            // exp2(x - m_loc), live across the barrier
  float ml0, ml1;                  // per-lane local maxima (log2 domain)
  {
    int jt = w;                         // j-tile 0..3
    f32x16 acc0, acc1;                  // i = la, i = 32+la
    #pragma unroll
    for (int i = 0; i < 16; i++){ acc0[i] = 0.f; acc1[i] = 0.f; }
    int arow  = (jt*32 + la) * AS;      // K row j
    int brow0 = (64 + la) * AS;         // Q row i (0..31)
    int brow1 = (96 + la) * AS;         // Q row i (32..63)
    __builtin_amdgcn_s_setprio(1);
    #pragma unroll
    for (int ks = 0; ks < 4; ks++){
      int o = ks*16 + coff;
      bf16x8 af = ld8(&A[arow  + o]);
      bf16x8 b0 = ld8(&A[brow0 + o]);
      bf16x8 b1 = ld8(&A[brow1 + o]);
      acc0 = __builtin_amdgcn_mfma_f32_32x32x16_bf16(af, b0, acc0, 0, 0, 0);
      acc1 = __builtin_amdgcn_mfma_f32_32x32x16_bf16(af, b1, acc1, 0, 0, 0);
    }
    __builtin_amdgcn_s_setprio(0);
    int pj[16]; float scj[16];
    #pragma unroll
    for (int g = 0; g < 4; g++){
      int j0 = jt*32 + g*8 + 4*hh;           // multiple of 4 -> 16B aligned
      int4   pv  = *(const int4*)(&pkey[j0]);
      float4 sv  = *(const float4*)(&sc[j0]);
      pj[g*4+0]=pv.x; pj[g*4+1]=pv.y; pj[g*4+2]=pv.z; pj[g*4+3]=pv.w;
      scj[g*4+0]=sv.x; scj[g*4+1]=sv.y; scj[g*4+2]=sv.z; scj[g*4+3]=sv.w;
    }
    int pi0 = pkey[64 + la], pi1 = pkey[96 + la];
    float x0[16], x1[16];
    #pragma unroll
    for (int reg = 0; reg < 16; reg++){
      float a0v = acc0[reg] * scj[reg];
      float a1v = acc1[reg] * scj[reg];
      // mask constants pre-scaled by LOG2E (exp2 domain)
      if (pi0 < pj[reg]) a0v = -1442695040.0f; else if (pi0 == pj[reg]) a0v = -144269.504f;
      if (pi1 < pj[reg]) a1v = -1442695040.0f; else if (pi1 == pj[reg]) a1v = -144269.504f;
      x0[reg] = a0v; x1[reg] = a1v;
    }
    { // pairwise max tree (depth 4; clang fuses to v_max3)
      float u0 = fmaxf(fmaxf(x0[0],x0[1]), fmaxf(x0[2],x0[3]));
      float u1 = fmaxf(fmaxf(x0[4],x0[5]), fmaxf(x0[6],x0[7]));
      float u2 = fmaxf(fmaxf(x0[8],x0[9]), fmaxf(x0[10],x0[11]));
      float u3 = fmaxf(fmaxf(x0[12],x0[13]), fmaxf(x0[14],x0[15]));
      ml0 = fmaxf(fmaxf(u0,u1), fmaxf(u2,u3));
      float w0 = fmaxf(fmaxf(x1[0],x1[1]), fmaxf(x1[2],x1[3]));
      float w1 = fmaxf(fmaxf(x1[4],x1[5]), fmaxf(x1[6],x1[7]));
      float w2 = fmaxf(fmaxf(x1[8],x1[9]), fmaxf(x1[10],x1[11]));
      float w3 = fmaxf(fmaxf(x1[12],x1[13]), fmaxf(x1[14],x1[15]));
      ml1 = fmaxf(fmaxf(w0,w1), fmaxf(w2,w3));
    }
    #pragma unroll
    for (int reg = 0; reg < 16; reg++){
      e0[reg] = ex2(x0[reg] - ml0);
      e1[reg] = ex2(x1[reg] - ml1);
    }
    // pairwise sum trees
    float s0, s1;
    {
      float u0 = (e0[0]+e0[1])+(e0[2]+e0[3]);
      float u1 = (e0[4]+e0[5])+(e0[6]+e0[7]);
      float u2 = (e0[8]+e0[9])+(e0[10]+e0[11]);
      float u3 = (e0[12]+e0[13])+(e0[14]+e0[15]);
      s0 = (u0+u1)+(u2+u3);
      float w0 = (e1[0]+e1[1])+(e1[2]+e1[3]);
      float w1 = (e1[4]+e1[5])+(e1[6]+e1[7]);
      float w2 = (e1[8]+e1[9])+(e1[10]+e1[11]);
      float w3 = (e1[12]+e1[13])+(e1[14]+e1[15]);
      s1 = (w0+w1)+(w2+w3);
    }
    // combine the two hh halves (same i, disjoint j) within the wave
    float om0 = __shfl_xor(ml0, 32, 64), os0 = __shfl_xor(s0, 32, 64);
    float om1 = __shfl_xor(ml1, 32, 64), os1 = __shfl_xor(s1, 32, 64);
    float m20 = fmaxf(ml0, om0);
    float m21 = fmaxf(ml1, om1);
    float s20 = s0 * ex2(ml0 - m20) + os0 * ex2(om0 - m20);
    float s21 = s1 * ex2(ml1 - m21) + os1 * ex2(om1 - m21);
    if (hh == 0){
      pm[jt*64 + la]      = m20;  ps[jt*64 + la]      = s20;
      pm[jt*64 + 32 + la] = m21;  ps[jt*64 + 32 + la] = s21;
    }
  }
  __syncthreads();

  // ---- phase 3: finalize softmax from partials, write probs; Vt build -----
  {
    int jt = w;
    // global (m, s) for i = la and i = 32+la
    float mg0 = pm[la],      mg1 = pm[32 + la];
    #pragma unroll
    for (int k = 1; k < 4; k++){
      mg0 = fmaxf(mg0, pm[k*64 + la]);
      mg1 = fmaxf(mg1, pm[k*64 + 32 + la]);
    }
    float sg0 = 0.f, sg1 = 0.f;
    #pragma unroll
    for (int k = 0; k < 4; k++){
      sg0 += ps[k*64 + la]      * ex2(pm[k*64 + la]      - mg0);
      sg1 += ps[k*64 + 32 + la] * ex2(pm[k*64 + 32 + la] - mg1);
    }
    float f0 = ex2(ml0 - mg0) * frcp(sg0);
    float f1 = ex2(ml1 - mg1) * frcp(sg1);
    #pragma unroll
    for (int g = 0; g < 4; g++){
      int j0 = jt*32 + g*8 + 4*hh;
      float4 rc = *(const float4*)(&rcnt[j0]);
      float p00 = e0[g*4+0]*f0*rc.x, p01 = e0[g*4+1]*f0*rc.y;
      float p02 = e0[g*4+2]*f0*rc.z, p03 = e0[g*4+3]*f0*rc.w;
      float p10 = e1[g*4+0]*f1*rc.x, p11 = e1[g*4+1]*f1*rc.y;
      float p12 = e1[g*4+2]*f1*rc.z, p13 = e1[g*4+3]*f1*rc.w;
      *(uint2*)(&SM[la*PS + j0])        = make_uint2(pk2bf(p00,p01), pk2bf(p02,p03));
      *(uint2*)(&SM[(32+la)*PS + j0])   = make_uint2(pk2bf(p10,p11), pk2bf(p12,p13));
    }
    if (w == 0 && hh == 0){
      // lse in natural-log domain: mg is log2, sg is domain-invariant
      lse_ws[((size_t)b*S_ + pkey[64 + la])*NR_ + r] = mg0 * LN2 + __logf(sg0);
      lse_ws[((size_t)b*S_ + pkey[96 + la])*NR_ + r] = mg1 * LN2 + __logf(sg1);
    }
  }
  { // Vt = V^T (pure bf16 interleave), overwriting A (reads done pre-barrier)
    u32 au[8] = {va0.x, va0.y, va0.z, va0.w, va1.x, va1.y, va1.z, va1.w};
    u32 bu[8] = {vb0.x, vb0.y, vb0.z, vb0.w, vb1.x, vb1.y, vb1.z, vb1.w};
    u32* vtp = (u32*)A;
    #pragma unroll
    for (int k = 0; k < 8; k++){
      int d0 = dgrp*16 + 2*k;
      u32 even = (au[k] & 0xffffu) | (bu[k] << 16);
      u32 odd  = (au[k] >> 16)     | (bu[k] & 0xffff0000u);
      vtp[ d0      * (VS/2) + jp] = even;
      vtp[(d0 + 1) * (VS/2) + jp] = odd;
    }
  }
  __syncthreads();

  // ---- phase 5: out^T = Vt.P^T via MFMA; LDS transpose; contiguous nt ----
  {
    int Mt2 = w >> 1, Nt2 = w & 1;
    f32x16 acc;
    #pragma unroll
    for (int i = 0; i < 16; i++) acc[i] = 0.f;
    int arow = (Mt2*32 + la) * VS;      // Vt row d, j contig
    int brow = (Nt2*32 + la) * PS;      // P row i, j contig
    __builtin_amdgcn_s_setprio(1);
    #pragma unroll
    for (int ks = 0; ks < 8; ks++){
      int o = ks*16 + coff;
      bf16x8 af = ld8(&A[arow + o]);
      bf16x8 bf = ld8(&SM[brow + o]);
      acc = __builtin_amdgcn_mfma_f32_32x32x16_bf16(af, bf, acc, 0, 0, 0);
    }
    __builtin_amdgcn_s_setprio(0);
    __syncthreads();                    // all waves done reading SM/A
    // transpose fragment into SM2 = SM reused as [i][OS] (i = slot-in-block)
    int i = Nt2*32 + la;
    int dbase = Mt2*32 + 4*hh;
    #pragma unroll
    for (int g = 0; g < 4; g++){
      *(uint2*)(&SM[i*OS + dbase + g*8]) =
          make_uint2(pk2bf(acc[4*g+0], acc[4*g+1]),
                     pk2bf(acc[4*g+2], acc[4*g+3]));
    }
  }
  __syncthreads();
  { // contiguous nt store: rows are slots n*64+i2 -> block output is 8KB run
    int i2 = t >> 2, qd = t & 3;        // 4 threads per 128B row
    uint4 x0 = *(const uint4*)(&SM[i2*OS + qd*16]);
    uint4 x1 = *(const uint4*)(&SM[i2*OS + qd*16 + 8]);
    u16* dst = att_ws + (((size_t)b*NR_ + r)*S_ + n*64 + i2)*(size_t)D_ + qd*16;
    nt_store16(dst,     x0);
    nt_store16(dst + 8, x1);
  }
}

// ---------------------------------------------------------------------------
// K4: per position softmax over round LSEs, weighted sum of round outputs.
// R13: att is slot-major; slot per (p,r) comes from chk (full slot). All 16
// lanes of a position share the slot -> att row reads stay 128B-coalesced.
// ---------------------------------------------------------------------------
__global__ __launch_bounds__(256) void k_comb(const float* __restrict__ lse_ws,
                                              const int* __restrict__ chk,
                                              const u16* __restrict__ att_ws,
                                              float* __restrict__ out){
  size_t idx4 = (size_t)blockIdx.x * 256 + threadIdx.x;  // over B*S*D/4
  size_t pd = idx4 >> 4;
  int d0 = (int)(idx4 & 15) * 4;
  int b = (int)(pd >> 11);            // S_ = 2048
  int p = (int)(pd & (S_ - 1));
  float4 lv = *(const float4*)(lse_ws + pd * 4);
  float m = fmaxf(fmaxf(lv.x, lv.y), fmaxf(lv.z, lv.w));
  float e0 = __expf(lv.x - m), e1 = __expf(lv.y - m);
  float e2 = __expf(lv.z - m), e3 = __expf(lv.w - m);
  float inv = frcp(e0 + e1 + e2 + e3);
  e0 *= inv; e1 *= inv; e2 *= inv; e3 *= inv;
  int s0 = chk[((size_t)b*NR_ + 0)*S_ + p];
  int s1 = chk[((size_t)b*NR_ + 1)*S_ + p];
  int s2 = chk[((size_t)b*NR_ + 2)*S_ + p];
  int s3 = chk[((size_t)b*NR_ + 3)*S_ + p];
  uint2 u0 = *(const uint2*)(att_ws + (((size_t)b*NR_ + 0)*S_ + s0)*(size_t)D_ + d0);
  uint2 u1 = *(const uint2*)(att_ws + (((size_t)b*NR_ + 1)*S_ + s1)*(size_t)D_ + d0);
  uint2 u2 = *(const uint2*)(att_ws + (((size_t)b*NR_ + 2)*S_ + s2)*(size_t)D_ + d0);
  uint2 u3 = *(const uint2*)(att_ws + (((size_t)b*NR_ + 3)*S_ + s3)*(size_t)D_ + d0);
  float4 o;
  float a0,b0,a1,b1,a2,b2,a3,b3;
  unpack2(u0.x,a0,b0); unpack2(u1.x,a1,b1); unpack2(u2.x,a2,b2); unpack2(u3.x,a3,b3);
  o.x = a0*e0 + a1*e1 + a2*e2 + a3*e3;
  o.y = b0*e0 + b1*e1 + b2*e2 + b3*e3;
  unpack2(u0.y,a0,b0); unpack2(u1.y,a1,b1); unpack2(u2.y,a2,b2); unpack2(u3.y,a3,b3);
  o.z = a0*e0 + a1*e1 + a2*e2 + a3*e3;
  o.w = b0*e0 + b1*e1 + b2*e2 + b3*e3;
  *(float4*)(out + pd * D_ + d0) = o;
}

// ---------------------------------------------------------------------------
extern "C" void kernel_launch(void* const* d_in, const int* in_sizes, int n_in,
                              void* d_out, int out_size, void* d_ws, size_t ws_size,
                              hipStream_t stream){
  const float* q = (const float*)d_in[0];   // (32,2048,64) f32
  const float* v = (const float*)d_in[1];   // (32,2048,64) f32
  const float* R = (const float*)d_in[2];   // (32,64,4,16) f32

  char* w = (char*)d_ws;
  int*   h    = (int*)  (w + 0);                     // 1 MB
  int*   sidx = (int*)  (w + (size_t)(1u << 20));    // 1 MB
  int*   chkA = (int*)  (w + (size_t)(2u << 20));    // 1 MB
  float* lse  = (float*)(w + (size_t)(3u << 20));    // 1 MB
  u16*   att  = (u16*)  (w + (size_t)(4u << 20));    // 32 MB
  u16*   qb   = (u16*)  (w + (size_t)(36u << 20));   // 8 MB bf16 q
  u16*   vbuf = (u16*)  (w + (size_t)(44u << 20));   // 8 MB bf16 v
  float* scq  = (float*)(w + (size_t)(52u << 20));   // 256 KB
  float* out  = (float*)d_out;

  k_hash <<<256,  256, 0, stream>>>(q, v, R, h, qb, vbuf, scq);
  k_sort <<<128,  256, 0, stream>>>(h, sidx, chkA);
  k_attn <<<4096, 256, 0, stream>>>(qb, vbuf, sidx, chkA, scq, lse, att);
  k_comb <<<4096, 256, 0, stream>>>(lse, chkA, att, out);
}